// Round 15
// baseline (234.412 us; speedup 1.0000x reference)
//
#include <hip/hip_runtime.h>
#include <cmath>

#define NEG_SLOPE 0.2f
#define DPB 128      // dsts per coarse bucket
#define EPB 4096     // edges per bucketing block

typedef unsigned int uint32;
typedef unsigned short ushort16;
typedef unsigned char uchar8;
typedef __attribute__((ext_vector_type(8))) short bf16x8;
typedef __attribute__((ext_vector_type(4))) float f32x4;
typedef __attribute__((ext_vector_type(2))) float f32x2;

__device__ __forceinline__ ushort16 f2bf(float x) {
    uint32 b = __float_as_uint(x);
    b += 0x7FFFu + ((b >> 16) & 1u);
    return (ushort16)(b >> 16);
}
__device__ __forceinline__ float bf2f_lo(uint32 u) { return __uint_as_float(u << 16); }
__device__ __forceinline__ float bf2f_hi(uint32 u) { return __uint_as_float(u & 0xFFFF0000u); }

// ---------------- B-matrix prep (both layers fused): bf16 [n][k], att-dot cols --------
__global__ void prep_B(const float* __restrict__ W1, const float* __restrict__ atts1,
                       const float* __restrict__ attd1,
                       const float* __restrict__ W2, const float* __restrict__ atts2,
                       const float* __restrict__ attd2,
                       ushort16* __restrict__ Bt1, ushort16* __restrict__ Bt2) {
    int idx = blockIdx.x * 256 + threadIdx.x;
    if (idx < 144 * 128) {
        int n = idx >> 7, k = idx & 127;
        float v = 0.f;
        if (n < 128) v = W1[k * 128 + n];
        else if (n < 132) { int h = n - 128; for (int c = 0; c < 32; c++) v += W1[k*128 + h*32 + c] * atts1[h*32 + c]; }
        else if (n < 136) { int h = n - 132; for (int c = 0; c < 32; c++) v += W1[k*128 + h*32 + c] * attd1[h*32 + c]; }
        Bt1[idx] = f2bf(v);
    } else {
        int j = idx - 144 * 128;
        if (j >= 48 * 128) return;
        int n = j >> 7, k = j & 127;
        float v = 0.f;
        if (n < 32) v = W2[k * 32 + n];
        else if (n == 32) { for (int c = 0; c < 32; c++) v += W2[k*32 + c] * atts2[c]; }
        else if (n == 33) { for (int c = 0; c < 32; c++) v += W2[k*32 + c] * attd2[c]; }
        Bt2[j] = f2bf(v);
    }
}

// ---------------- MFMA GEMM: K=128, N = NT*16 cols (last tile = att-dot cols) ---------
template<int NT, int NH, bool XBF, bool OUT8>
__global__ __launch_bounds__(256) void gemm_mfma(
    const void* __restrict__ Xv, const ushort16* __restrict__ Bt,
    void* __restrict__ Houtv, float* __restrict__ asd, int M)
{
    constexpr int HT = NT - 1;
    constexpr int KP = 136;
    __shared__ ushort16 Bl[NT * 16 * KP];
    const int t = threadIdx.x;
    for (int i = t; i < NT * 16 * 32; i += 256) {
        int n = i >> 5, k4 = i & 31;
        uint2 v = *(const uint2*)&Bt[n * 128 + k4 * 4];
        *(uint2*)&Bl[n * KP + k4 * 4] = v;
    }
    __syncthreads();
    const int wave = t >> 6, lane = t & 63;
    const int lrow = lane & 15, lgrp = lane >> 4;
    const int ntiles = (M + 127) >> 7;
    const float* Xf = (const float*)Xv;
    const ushort16* Xb = (const ushort16*)Xv;

    for (int tile = blockIdx.x; tile < ntiles; tile += gridDim.x) {
        const int rbase = tile * 128 + wave * 32;
        f32x4 acc[2][NT];
        #pragma unroll
        for (int rs = 0; rs < 2; rs++)
            #pragma unroll
            for (int n = 0; n < NT; n++) acc[rs][n] = (f32x4){0.f, 0.f, 0.f, 0.f};

        for (int kk = 0; kk < 4; kk++) {
            bf16x8 bf[NT];
            #pragma unroll
            for (int n = 0; n < NT; n++)
                bf[n] = *(const bf16x8*)&Bl[(n * 16 + lrow) * KP + kk * 32 + lgrp * 8];
            #pragma unroll
            for (int rs = 0; rs < 2; rs++) {
                int row = rbase + rs * 16 + lrow;
                int rowc = row < M ? row : M - 1;
                bf16x8 af;
                if constexpr (XBF) {
                    af = *(const bf16x8*)&Xb[(long)rowc * 128 + kk * 32 + lgrp * 8];
                } else {
                    const float* xp = Xf + (long)rowc * 128 + kk * 32 + lgrp * 8;
                    float4 f0 = *(const float4*)xp;
                    float4 f1 = *(const float4*)(xp + 4);
                    union { uint32 u[4]; bf16x8 v; } pk;
                    pk.u[0] = (uint32)f2bf(f0.x) | ((uint32)f2bf(f0.y) << 16);
                    pk.u[1] = (uint32)f2bf(f0.z) | ((uint32)f2bf(f0.w) << 16);
                    pk.u[2] = (uint32)f2bf(f1.x) | ((uint32)f2bf(f1.y) << 16);
                    pk.u[3] = (uint32)f2bf(f1.z) | ((uint32)f2bf(f1.w) << 16);
                    af = pk.v;
                }
                #pragma unroll
                for (int n = 0; n < NT; n++)
                    acc[rs][n] = __builtin_amdgcn_mfma_f32_16x16x32_bf16(af, bf[n], acc[rs][n], 0, 0, 0);
            }
        }
        #pragma unroll
        for (int rs = 0; rs < 2; rs++) {
            #pragma unroll
            for (int r = 0; r < 4; r++) {
                const int row = rbase + rs * 16 + lgrp * 4 + r;
                if (row < M) {
                    if constexpr (OUT8) {
                        uchar8* H8 = (uchar8*)Houtv;
                        #pragma unroll
                        for (int n = 0; n < HT; n++) {
                            int pk = __builtin_amdgcn_cvt_pk_fp8_f32(acc[rs][n][r], 0.f, 0, false);
                            H8[(long)row * (HT * 16) + n * 16 + lrow] = (uchar8)pk;
                        }
                    } else {
                        ushort16* Hh = (ushort16*)Houtv;
                        #pragma unroll
                        for (int n = 0; n < HT; n++)
                            Hh[(long)row * (HT * 16) + n * 16 + lrow] = f2bf(acc[rs][n][r]);
                    }
                    if (lrow < 2 * NH)
                        asd[(long)row * (2 * NH) + lrow] = acc[rs][NT - 1][r];
                }
            }
        }
    }
}

// ================= CSR build via two-level multisplit (no global atomics) =============
__global__ __launch_bounds__(256) void buck_hist_k(
    const int* __restrict__ ei, int E, int Etot,
    int* __restrict__ cnt_bb, int NBUK_, int NBLK_)
{
    __shared__ int hist[1024];
    const int b = blockIdx.x, t = threadIdx.x;
    for (int i = t; i < NBUK_; i += 256) hist[i] = 0;
    __syncthreads();
    const int e0 = b * EPB;
    for (int i = t; i < EPB; i += 256) {
        int e = e0 + i;
        if (e < Etot) {
            int d = (e < E) ? ei[E + e] : (e - E);
            atomicAdd(&hist[d >> 7], 1);
        }
    }
    __syncthreads();
    for (int i = t; i < NBUK_; i += 256) cnt_bb[(size_t)i * NBLK_ + b] = hist[i];
}

__global__ __launch_bounds__(256) void buck_scan_row_k(
    int* __restrict__ cnt_bb, int* __restrict__ rowTot, int NBLK_)
{
    __shared__ int tmp[256];
    const int k = blockIdx.x, t = threadIdx.x;
    int* row = cnt_bb + (size_t)k * NBLK_;
    const int base = t * 4;
    int v[4]; int s = 0;
    #pragma unroll
    for (int j = 0; j < 4; j++) { v[j] = (base + j < NBLK_) ? row[base + j] : 0; s += v[j]; }
    tmp[t] = s; __syncthreads();
    for (int off = 1; off < 256; off <<= 1) {
        int x = (t >= off) ? tmp[t - off] : 0;
        __syncthreads();
        tmp[t] += x;
        __syncthreads();
    }
    int run = tmp[t] - s;
    if (t == 255) rowTot[k] = tmp[255];
    #pragma unroll
    for (int j = 0; j < 4; j++) { if (base + j < NBLK_) row[base + j] = run; run += v[j]; }
}

__global__ __launch_bounds__(256) void buck_base_k(
    const int* __restrict__ rowTot, int* __restrict__ bucketBase, int NBUK_)
{
    __shared__ int tmp[256];
    const int t = threadIdx.x;
    const int base = t * 4;
    int v[4]; int s = 0;
    #pragma unroll
    for (int j = 0; j < 4; j++) {
        v[j] = (base + j < NBUK_) ? ((rowTot[base + j] + 3 * DPB + 7) & ~7) : 0;
        s += v[j];
    }
    tmp[t] = s; __syncthreads();
    for (int off = 1; off < 256; off <<= 1) {
        int x = (t >= off) ? tmp[t - off] : 0;
        __syncthreads();
        tmp[t] += x;
        __syncthreads();
    }
    int run = tmp[t] - s;
    #pragma unroll
    for (int j = 0; j < 4; j++) { if (base + j < NBUK_) bucketBase[base + j] = run; run += v[j]; }
}

__global__ __launch_bounds__(256) void buck_scatter_k(
    const int* __restrict__ ei, int E, int Etot,
    const int* __restrict__ cnt_bb, const int* __restrict__ bucketBase,
    uint32* __restrict__ be, int NBUK_, int NBLK_)
{
    __shared__ int cur[1024];
    const int b = blockIdx.x, t = threadIdx.x;
    for (int i = t; i < NBUK_; i += 256)
        cur[i] = bucketBase[i] + cnt_bb[(size_t)i * NBLK_ + b];
    __syncthreads();
    const int e0 = b * EPB;
    for (int i = t; i < EPB; i += 256) {
        int e = e0 + i;
        if (e < Etot) {
            int srcv, d;
            if (e < E) { srcv = ei[e]; d = ei[E + e]; } else { srcv = d = e - E; }
            int slot = atomicAdd(&cur[d >> 7], 1);
            be[slot] = (uint32)srcv | ((uint32)(d & (DPB - 1)) << 20);
        }
    }
}

// Per bucket: hist/scan (x4-padded), write indptr/count, rank+scatter into LDS image,
// flush CSR coalesced AND compute layer-1 p planes (fused edge_p).
// CSR stores PRE-SHIFTED byte offsets (src<<7); pad slots: csr=0, p=0.
// No-max softmax is safe: |logit| < ~5 for this model, exp cannot overflow.
__global__ __launch_bounds__(256) void buck_finalize_k(
    const uint32* __restrict__ be, const int* __restrict__ rowTot,
    const int* __restrict__ bucketBase, const float* __restrict__ asd1,
    int* __restrict__ csr, int* __restrict__ indptr, int* __restrict__ count,
    ushort16* __restrict__ p1h, int N_, int EP)
{
    __shared__ int lhist[DPB];
    __shared__ int lptr[DPB];
    __shared__ int lcur[DPB];
    __shared__ int stmp[DPB];
    __shared__ int img[6144];
    __shared__ short slot2d[6144];
    __shared__ float4 adl[DPB];
    __shared__ int paddedTotS;
    const int k = blockIdx.x, t = threadIdx.x;
    const int baseG = bucketBase[k];
    const int Mk = rowTot[k];
    if (t < DPB) lhist[t] = 0;
    __syncthreads();
    for (int i = t; i < Mk; i += 256) atomicAdd(&lhist[be[baseG + i] >> 20], 1);
    __syncthreads();
    int myp = (t < DPB) ? ((lhist[t] + 3) & ~3) : 0;
    if (t < DPB) stmp[t] = myp;
    __syncthreads();
    for (int off = 1; off < DPB; off <<= 1) {
        int x = (t < DPB && t >= off) ? stmp[t - off] : 0;
        __syncthreads();
        if (t < DPB) stmp[t] += x;
        __syncthreads();
    }
    if (t < DPB) { lptr[t] = stmp[t] - myp; lcur[t] = stmp[t] - myp; }
    if (t == DPB - 1) paddedTotS = stmp[t];
    __syncthreads();
    const int paddedTot = paddedTotS < 6144 ? paddedTotS : 6144;
    for (int i = t; i < paddedTot; i += 256) { img[i] = 0; slot2d[i] = -1; }
    if (t < DPB) {
        int d = k * DPB + t;
        if (d < N_) {
            count[d] = lhist[t];
            indptr[d] = baseG + lptr[t];
            adl[t] = *(const float4*)&asd1[(size_t)d * 8 + 4];
        }
    }
    __syncthreads();
    for (int i = t; i < Mk; i += 256) {
        uint32 pk = be[baseG + i];
        int dloc = (int)(pk >> 20);
        int slot = atomicAdd(&lcur[dloc], 1);
        if (slot < 6144) {
            img[slot] = (int)((pk & 0xFFFFFu) << 7);   // pre-shifted byte offset
            slot2d[slot] = (short)dloc;
        }
    }
    __syncthreads();
    const char* asdb = (const char*)asd1;
    for (int i = t; i < paddedTot; i += 256) {
        const int sb = img[i];
        csr[baseG + i] = sb;
        const int dloc = slot2d[i];
        ushort16 r0 = 0, r1 = 0, r2 = 0, r3 = 0;
        if (dloc >= 0) {
            float4 as = *(const float4*)(asdb + (((uint32)sb) >> 2));   // src*32
            float4 ad = adl[dloc];
            float e0 = as.x + ad.x, e1 = as.y + ad.y, e2 = as.z + ad.z, e3 = as.w + ad.w;
            e0 = e0 >= 0.f ? e0 : NEG_SLOPE * e0;
            e1 = e1 >= 0.f ? e1 : NEG_SLOPE * e1;
            e2 = e2 >= 0.f ? e2 : NEG_SLOPE * e2;
            e3 = e3 >= 0.f ? e3 : NEG_SLOPE * e3;
            r0 = f2bf(__expf(e0)); r1 = f2bf(__expf(e1));
            r2 = f2bf(__expf(e2)); r3 = f2bf(__expf(e3));
        }
        const int pos = baseG + i;
        p1h[pos] = r0;
        p1h[EP + pos] = r1;
        p1h[2 * EP + pos] = r2;
        p1h[3 * EP + pos] = r3;
    }
}

// ================= layer-2 per-edge softmax weights ===================================
__global__ __launch_bounds__(256) void edge_p2_k(
    const int* __restrict__ csr, const int* __restrict__ indptr, const int* __restrict__ count,
    const float* __restrict__ asd2, ushort16* __restrict__ p2, int N)
{
    int wave = threadIdx.x >> 6, lane = threadIdx.x & 63;
    int dst = blockIdx.x * 4 + wave;
    if (dst >= N) return;
    const char* asdb = (const char*)asd2;
    const int start = indptr[dst], cnt = count[dst];
    const int cntp = (cnt + 3) & ~3;
    const float ad = *(const float*)(asdb + (((uint32)dst << 3) | 4u));
    for (int k = lane; k < cntp; k += 64) {
        ushort16 r = 0;
        if (k < cnt) {
            uint32 sb = (uint32)csr[start + k];
            float el = *(const float*)(asdb + (sb >> 4)) + ad;   // src*8
            el = el >= 0.f ? el : NEG_SLOPE * el;
            r = f2bf(__expf(el));
        }
        p2[start + k] = r;
    }
}

// ---------------- layer-1 aggregation: dual-dst per wave, 16 gathers in flight -------
// Lane l -> channels 2l,2l+1, head = l>>4; csr holds src<<7; addr = sb | lane*2.
__global__ __launch_bounds__(256) void agg_flash_h4(
    const int* __restrict__ csr, const ushort16* __restrict__ p1h,
    const int* __restrict__ indptr, const int* __restrict__ count,
    const uchar8* __restrict__ H8, const float* __restrict__ b1,
    uint32* __restrict__ Out, int N, int EP)
{
    int wave = threadIdx.x >> 6, lane = threadIdx.x & 63;
    int d0 = (blockIdx.x * 4 + wave) * 2;
    if (d0 >= N) return;
    const int d1 = d0 + 1;
    const char* Hb = (const char*)H8;
    const int head = lane >> 4;
    const uint32 ch2 = (uint32)(lane * 2);
    const int start0 = indptr[d0];
    const int cntp0 = (count[d0] + 3) & ~3;
    int start1 = 0, cntp1 = 0;
    if (d1 < N) { start1 = indptr[d1]; cntp1 = (count[d1] + 3) & ~3; }
    const ushort16* ppb = p1h + (size_t)head * EP;
    const int* cp0 = csr + start0;
    const int* cp1 = csr + start1;
    const ushort16* pp0 = ppb + start0;
    const ushort16* pp1 = ppb + start1;
    float s0 = 0.f, a00 = 0.f, a01 = 0.f;
    float s1 = 0.f, a10 = 0.f, a11 = 0.f;

    auto do8 = [&](const int* cp, const ushort16* pp, int k,
                   float& s, float& a0, float& a1) {
        const int4 svA = *(const int4*)&cp[k];
        const int4 svB = *(const int4*)&cp[k + 4];
        const uint2 pwA = *(const uint2*)&pp[k];
        const uint2 pwB = *(const uint2*)&pp[k + 4];
        const uint32 u0 = *(const ushort16*)(Hb + ((uint32)svA.x | ch2));
        const uint32 u1 = *(const ushort16*)(Hb + ((uint32)svA.y | ch2));
        const uint32 u2 = *(const ushort16*)(Hb + ((uint32)svA.z | ch2));
        const uint32 u3 = *(const ushort16*)(Hb + ((uint32)svA.w | ch2));
        const uint32 u4 = *(const ushort16*)(Hb + ((uint32)svB.x | ch2));
        const uint32 u5 = *(const ushort16*)(Hb + ((uint32)svB.y | ch2));
        const uint32 u6 = *(const ushort16*)(Hb + ((uint32)svB.z | ch2));
        const uint32 u7 = *(const ushort16*)(Hb + ((uint32)svB.w | ch2));
        const f32x2 h0 = __builtin_amdgcn_cvt_pk_f32_fp8((int)u0, false);
        const f32x2 h1 = __builtin_amdgcn_cvt_pk_f32_fp8((int)u1, false);
        const f32x2 h2 = __builtin_amdgcn_cvt_pk_f32_fp8((int)u2, false);
        const f32x2 h3 = __builtin_amdgcn_cvt_pk_f32_fp8((int)u3, false);
        const f32x2 h4 = __builtin_amdgcn_cvt_pk_f32_fp8((int)u4, false);
        const f32x2 h5 = __builtin_amdgcn_cvt_pk_f32_fp8((int)u5, false);
        const f32x2 h6 = __builtin_amdgcn_cvt_pk_f32_fp8((int)u6, false);
        const f32x2 h7 = __builtin_amdgcn_cvt_pk_f32_fp8((int)u7, false);
        const float p0 = bf2f_lo(pwA.x), p1v = bf2f_hi(pwA.x);
        const float p2v = bf2f_lo(pwA.y), p3v = bf2f_hi(pwA.y);
        const float p4v = bf2f_lo(pwB.x), p5v = bf2f_hi(pwB.x);
        const float p6v = bf2f_lo(pwB.y), p7v = bf2f_hi(pwB.y);
        s += ((p0 + p1v) + (p2v + p3v)) + ((p4v + p5v) + (p6v + p7v));
        a0 += p0 * h0[0];  a1 += p0 * h0[1];
        a0 += p1v * h1[0]; a1 += p1v * h1[1];
        a0 += p2v * h2[0]; a1 += p2v * h2[1];
        a0 += p3v * h3[0]; a1 += p3v * h3[1];
        a0 += p4v * h4[0]; a1 += p4v * h4[1];
        a0 += p5v * h5[0]; a1 += p5v * h5[1];
        a0 += p6v * h6[0]; a1 += p6v * h6[1];
        a0 += p7v * h7[0]; a1 += p7v * h7[1];
    };
    auto do4 = [&](const int* cp, const ushort16* pp, int k,
                   float& s, float& a0, float& a1) {
        const int4 sv = *(const int4*)&cp[k];
        const uint2 pw = *(const uint2*)&pp[k];
        const uint32 u0 = *(const ushort16*)(Hb + ((uint32)sv.x | ch2));
        const uint32 u1 = *(const ushort16*)(Hb + ((uint32)sv.y | ch2));
        const uint32 u2 = *(const ushort16*)(Hb + ((uint32)sv.z | ch2));
        const uint32 u3 = *(const ushort16*)(Hb + ((uint32)sv.w | ch2));
        const f32x2 h0 = __builtin_amdgcn_cvt_pk_f32_fp8((int)u0, false);
        const f32x2 h1 = __builtin_amdgcn_cvt_pk_f32_fp8((int)u1, false);
        const f32x2 h2 = __builtin_amdgcn_cvt_pk_f32_fp8((int)u2, false);
        const f32x2 h3 = __builtin_amdgcn_cvt_pk_f32_fp8((int)u3, false);
        const float p0 = bf2f_lo(pw.x), p1v = bf2f_hi(pw.x);
        const float p2v = bf2f_lo(pw.y), p3v = bf2f_hi(pw.y);
        s += (p0 + p1v) + (p2v + p3v);
        a0 += p0 * h0[0];  a1 += p0 * h0[1];
        a0 += p1v * h1[0]; a1 += p1v * h1[1];
        a0 += p2v * h2[0]; a1 += p2v * h2[1];
        a0 += p3v * h3[0]; a1 += p3v * h3[1];
    };

    int k0 = 0, k1 = 0;
    // joint phase: 16 gathers in flight
    while (k0 + 8 <= cntp0 && k1 + 8 <= cntp1) {
        do8(cp0, pp0, k0, s0, a00, a01);
        do8(cp1, pp1, k1, s1, a10, a11);
        k0 += 8; k1 += 8;
    }
    // drains
    for (; k0 + 8 <= cntp0; k0 += 8) do8(cp0, pp0, k0, s0, a00, a01);
    for (; k1 + 8 <= cntp1; k1 += 8) do8(cp1, pp1, k1, s1, a10, a11);
    if (k0 < cntp0) do4(cp0, pp0, k0, s0, a00, a01);
    if (k1 < cntp1) do4(cp1, pp1, k1, s1, a10, a11);

    const float2 bb = *(const float2*)&b1[ch2];
    {
        const float inv = 1.f / s0;
        float o0 = fmaxf(a00 * inv + bb.x, 0.f);
        float o1 = fmaxf(a01 * inv + bb.y, 0.f);
        Out[(long)d0 * 64 + lane] = (uint32)f2bf(o0) | ((uint32)f2bf(o1) << 16);
    }
    if (d1 < N) {
        const float inv = 1.f / s1;
        float o0 = fmaxf(a10 * inv + bb.x, 0.f);
        float o1 = fmaxf(a11 * inv + bb.y, 0.f);
        Out[(long)d1 * 64 + lane] = (uint32)f2bf(o0) | ((uint32)f2bf(o1) << 16);
    }
}

// ---------------- layer-2 aggregation: fp8 H2, 4 groups x 4-edge unroll ---------------
// csr holds src<<7; addr = (sb>>2) | c2*2.
__global__ __launch_bounds__(256) void agg_flash_h1(
    const int* __restrict__ csr, const ushort16* __restrict__ p2,
    const int* __restrict__ indptr, const int* __restrict__ count,
    const uchar8* __restrict__ H8, float* __restrict__ Out, int N)
{
    int wave = threadIdx.x >> 6, lane = threadIdx.x & 63;
    int dst = blockIdx.x * 4 + wave;
    if (dst >= N) return;
    const char* Hb = (const char*)H8;
    const int c2 = lane & 15, grp = lane >> 4;
    const uint32 cb = (uint32)(c2 * 2);
    const int start = indptr[dst];
    const int cntp = (count[dst] + 3) & ~3;
    float s = 0.f, a0 = 0.f, a1 = 0.f;
    for (int k = grp * 4; k < cntp; k += 16) {
        const int4  sv = *(const int4*)&csr[start + k];
        const uint2 pv = *(const uint2*)&p2[start + k];
        const uint32 u0 = *(const ushort16*)(Hb + (((uint32)sv.x >> 2) | cb));
        const uint32 u1 = *(const ushort16*)(Hb + (((uint32)sv.y >> 2) | cb));
        const uint32 u2 = *(const ushort16*)(Hb + (((uint32)sv.z >> 2) | cb));
        const uint32 u3 = *(const ushort16*)(Hb + (((uint32)sv.w >> 2) | cb));
        const f32x2 h0 = __builtin_amdgcn_cvt_pk_f32_fp8((int)u0, false);
        const f32x2 h1 = __builtin_amdgcn_cvt_pk_f32_fp8((int)u1, false);
        const f32x2 h2 = __builtin_amdgcn_cvt_pk_f32_fp8((int)u2, false);
        const f32x2 h3 = __builtin_amdgcn_cvt_pk_f32_fp8((int)u3, false);
        float q0 = bf2f_lo(pv.x), q1 = bf2f_hi(pv.x);
        float q2 = bf2f_lo(pv.y), q3 = bf2f_hi(pv.y);
        s += (q0 + q1) + (q2 + q3);
        a0 += q0 * h0[0]; a1 += q0 * h0[1];
        a0 += q1 * h1[0]; a1 += q1 * h1[1];
        a0 += q2 * h2[0]; a1 += q2 * h2[1];
        a0 += q3 * h3[0]; a1 += q3 * h3[1];
    }
    s  += __shfl_xor(s, 16, 64);  s  += __shfl_xor(s, 32, 64);
    a0 += __shfl_xor(a0, 16, 64); a0 += __shfl_xor(a0, 32, 64);
    a1 += __shfl_xor(a1, 16, 64); a1 += __shfl_xor(a1, 32, 64);
    if (grp == 0) {
        const float inv = 1.f / s;
        float2 o; o.x = a0 * inv; o.y = a1 * inv;
        *(float2*)&Out[(long)dst * 32 + c2 * 2] = o;
    }
}

// ---------------- fused mean-pool + FC: one block per graph, zero atomics -------------
__global__ __launch_bounds__(256) void pool_fc_kernel(
    const float* __restrict__ Agg2, const float* __restrict__ b2,
    const int* __restrict__ batch,
    const float* __restrict__ Wfc, const float* __restrict__ bfc,
    float* __restrict__ out, int N)
{
    __shared__ float part[8][32];
    const int g = blockIdx.x;
    const int t = threadIdx.x;
    const int c = t & 31, grp = t >> 5;

    int lo = 0, hi = N;
    while (lo < hi) { int mid = (lo + hi) >> 1; if (batch[mid] < g) lo = mid + 1; else hi = mid; }
    const int start = lo;
    hi = N;
    while (lo < hi) { int mid = (lo + hi) >> 1; if (batch[mid] <= g) lo = mid + 1; else hi = mid; }
    const int end = lo;

    const float bc = b2[c];
    float acc = 0.f;
    for (int i = start + grp; i < end; i += 8)
        acc += fmaxf(Agg2[(long)i * 32 + c] + bc, 0.f);
    part[grp][c] = acc;
    __syncthreads();
    if (t < 32) {
        float s = 0.f;
        #pragma unroll
        for (int r = 0; r < 8; r++) s += part[r][c];
        const float cnt = fmaxf((float)(end - start), 1.f);
        float v = (s / cnt) * Wfc[c];
        #pragma unroll
        for (int m = 16; m >= 1; m >>= 1) v += __shfl_xor(v, m, 64);
        if (c == 0) out[g] = v + bfc[0];
    }
}

extern "C" void kernel_launch(void* const* d_in, const int* in_sizes, int n_in,
                              void* d_out, int out_size, void* d_ws, size_t ws_size,
                              hipStream_t stream)
{
    const float* x     = (const float*)d_in[0];
    const int*   ei    = (const int*)d_in[1];
    const int*   batch = (const int*)d_in[2];
    const float* W1    = (const float*)d_in[3];
    const float* atts1 = (const float*)d_in[4];
    const float* attd1 = (const float*)d_in[5];
    const float* b1    = (const float*)d_in[6];
    const float* W2    = (const float*)d_in[7];
    const float* atts2 = (const float*)d_in[8];
    const float* attd2 = (const float*)d_in[9];
    const float* b2    = (const float*)d_in[10];
    const float* Wfc   = (const float*)d_in[11];
    const float* bfc   = (const float*)d_in[12];
    float* out = (float*)d_out;

    const int N = in_sizes[0] / 128;
    const int E = in_sizes[1] / 2;
    const int Etot = E + N;
    const int G = out_size;
    const int NBUK = (N + DPB - 1) / DPB;
    const int NBLK = (Etot + EPB - 1) / EPB;
    const int CSRCAP = (Etot + NBUK * (3 * DPB + 8) + 7) & ~7;
    const int ntiles = (N + 127) >> 7;

    float* w = (float*)d_ws;
    uchar8* h1   = (uchar8*)w; w += (size_t)N * 32;   // N*128 fp8
    uchar8* h2   = (uchar8*)w; w += (size_t)N * 8;    // N*32 fp8
    uint32* agg1 = (uint32*)w; w += (size_t)N * 64;   // N*128 bf16 (= relu'd layer-2 X)
    float* agg2 = w; w += (size_t)N * 32;
    float* asd1 = w; w += (size_t)N * 8;              // {as[4], ad[4]}
    float* asd2 = w; w += (size_t)N * 2;              // {as, ad}
    ushort16* Bt1 = (ushort16*)w; w += (144 * 128) / 2;
    ushort16* Bt2 = (ushort16*)w; w += (48 * 128) / 2;
    int* count  = (int*)w; w += N;
    int* indptr = (int*)w; w += N;
    int* cnt_bb = (int*)w; w += (size_t)NBUK * NBLK;
    int* rowTot = (int*)w; w += NBUK;
    int* bucketBase = (int*)w; w += NBUK;
    uint32* be  = (uint32*)w; w += CSRCAP;
    int* csr    = (int*)w; w += CSRCAP;
    ushort16* p1h = (ushort16*)w; w += (size_t)CSRCAP * 2;  // 4 head planes bf16
    ushort16* p2  = (ushort16*)w; w += CSRCAP / 2;

    // prep B matrices (both layers, one kernel)
    prep_B<<<(192 * 128 + 255) / 256, 256, 0, stream>>>(W1, atts1, attd1, W2, atts2, attd2, Bt1, Bt2);

    // layer-1 GEMM (MFMA bf16): fp8 h1 + f32 asd1; exact tile grid
    gemm_mfma<9, 4, false, true><<<ntiles, 256, 0, stream>>>(x, Bt1, h1, asd1, N);

    // CSR build: two-level multisplit, no global atomics; csr holds src<<7;
    // finalize also emits layer-1 p planes (fused)
    buck_hist_k<<<NBLK, 256, 0, stream>>>(ei, E, Etot, cnt_bb, NBUK, NBLK);
    buck_scan_row_k<<<NBUK, 256, 0, stream>>>(cnt_bb, rowTot, NBLK);
    buck_base_k<<<1, 256, 0, stream>>>(rowTot, bucketBase, NBUK);
    buck_scatter_k<<<NBLK, 256, 0, stream>>>(ei, E, Etot, cnt_bb, bucketBase, be, NBUK, NBLK);
    buck_finalize_k<<<NBUK, 256, 0, stream>>>(be, rowTot, bucketBase, asd1,
                                              csr, indptr, count, p1h, N, CSRCAP);

    // layer-1 aggregation (dual-dst per wave)
    agg_flash_h4<<<(N + 7) / 8, 256, 0, stream>>>(csr, p1h, indptr, count, h1, b1, agg1, N, CSRCAP);

    // layer-2 GEMM (MFMA bf16, bf16 A direct): fp8 h2 + f32 asd2
    gemm_mfma<3, 1, true, true><<<ntiles, 256, 0, stream>>>(agg1, Bt2, h2, asd2, N);
    edge_p2_k<<<(N + 3) / 4, 256, 0, stream>>>(csr, indptr, count, asd2, p2, N);
    agg_flash_h1<<<(N + 3) / 4, 256, 0, stream>>>(csr, p2, indptr, count, h2, agg2, N);

    // fused mean-pool + FC
    pool_fc_kernel<<<G, 256, 0, stream>>>(agg2, b2, batch, Wfc, bfc, out, N);
}

// Round 16
// 231.566 us; speedup vs baseline: 1.0123x; 1.0123x over previous
//
#include <hip/hip_runtime.h>
#include <cmath>

#define NEG_SLOPE 0.2f
#define DPB 128      // dsts per coarse bucket
#define EPB 4096     // edges per bucketing block

typedef unsigned int uint32;
typedef unsigned short ushort16;
typedef unsigned char uchar8;
typedef __attribute__((ext_vector_type(8))) short bf16x8;
typedef __attribute__((ext_vector_type(4))) float f32x4;
typedef __attribute__((ext_vector_type(2))) float f32x2;

__device__ __forceinline__ ushort16 f2bf(float x) {
    uint32 b = __float_as_uint(x);
    b += 0x7FFFu + ((b >> 16) & 1u);
    return (ushort16)(b >> 16);
}
__device__ __forceinline__ float bf2f_lo(uint32 u) { return __uint_as_float(u << 16); }
__device__ __forceinline__ float bf2f_hi(uint32 u) { return __uint_as_float(u & 0xFFFF0000u); }

// ---------------- B-matrix prep (both layers fused): bf16 [n][k], att-dot cols --------
__global__ void prep_B(const float* __restrict__ W1, const float* __restrict__ atts1,
                       const float* __restrict__ attd1,
                       const float* __restrict__ W2, const float* __restrict__ atts2,
                       const float* __restrict__ attd2,
                       ushort16* __restrict__ Bt1, ushort16* __restrict__ Bt2) {
    int idx = blockIdx.x * 256 + threadIdx.x;
    if (idx < 144 * 128) {
        int n = idx >> 7, k = idx & 127;
        float v = 0.f;
        if (n < 128) v = W1[k * 128 + n];
        else if (n < 132) { int h = n - 128; for (int c = 0; c < 32; c++) v += W1[k*128 + h*32 + c] * atts1[h*32 + c]; }
        else if (n < 136) { int h = n - 132; for (int c = 0; c < 32; c++) v += W1[k*128 + h*32 + c] * attd1[h*32 + c]; }
        Bt1[idx] = f2bf(v);
    } else {
        int j = idx - 144 * 128;
        if (j >= 48 * 128) return;
        int n = j >> 7, k = j & 127;
        float v = 0.f;
        if (n < 32) v = W2[k * 32 + n];
        else if (n == 32) { for (int c = 0; c < 32; c++) v += W2[k*32 + c] * atts2[c]; }
        else if (n == 33) { for (int c = 0; c < 32; c++) v += W2[k*32 + c] * attd2[c]; }
        Bt2[j] = f2bf(v);
    }
}

// ---------------- MFMA GEMM: K=128, N = NT*16 cols (last tile = att-dot cols) ---------
template<int NT, int NH, bool XBF, bool OUT8>
__global__ __launch_bounds__(256) void gemm_mfma(
    const void* __restrict__ Xv, const ushort16* __restrict__ Bt,
    void* __restrict__ Houtv, float* __restrict__ asd, int M)
{
    constexpr int HT = NT - 1;
    constexpr int KP = 136;
    __shared__ ushort16 Bl[NT * 16 * KP];
    const int t = threadIdx.x;
    for (int i = t; i < NT * 16 * 32; i += 256) {
        int n = i >> 5, k4 = i & 31;
        uint2 v = *(const uint2*)&Bt[n * 128 + k4 * 4];
        *(uint2*)&Bl[n * KP + k4 * 4] = v;
    }
    __syncthreads();
    const int wave = t >> 6, lane = t & 63;
    const int lrow = lane & 15, lgrp = lane >> 4;
    const int ntiles = (M + 127) >> 7;
    const float* Xf = (const float*)Xv;
    const ushort16* Xb = (const ushort16*)Xv;

    for (int tile = blockIdx.x; tile < ntiles; tile += gridDim.x) {
        const int rbase = tile * 128 + wave * 32;
        f32x4 acc[2][NT];
        #pragma unroll
        for (int rs = 0; rs < 2; rs++)
            #pragma unroll
            for (int n = 0; n < NT; n++) acc[rs][n] = (f32x4){0.f, 0.f, 0.f, 0.f};

        for (int kk = 0; kk < 4; kk++) {
            bf16x8 bf[NT];
            #pragma unroll
            for (int n = 0; n < NT; n++)
                bf[n] = *(const bf16x8*)&Bl[(n * 16 + lrow) * KP + kk * 32 + lgrp * 8];
            #pragma unroll
            for (int rs = 0; rs < 2; rs++) {
                int row = rbase + rs * 16 + lrow;
                int rowc = row < M ? row : M - 1;
                bf16x8 af;
                if constexpr (XBF) {
                    af = *(const bf16x8*)&Xb[(long)rowc * 128 + kk * 32 + lgrp * 8];
                } else {
                    const float* xp = Xf + (long)rowc * 128 + kk * 32 + lgrp * 8;
                    float4 f0 = *(const float4*)xp;
                    float4 f1 = *(const float4*)(xp + 4);
                    union { uint32 u[4]; bf16x8 v; } pk;
                    pk.u[0] = (uint32)f2bf(f0.x) | ((uint32)f2bf(f0.y) << 16);
                    pk.u[1] = (uint32)f2bf(f0.z) | ((uint32)f2bf(f0.w) << 16);
                    pk.u[2] = (uint32)f2bf(f1.x) | ((uint32)f2bf(f1.y) << 16);
                    pk.u[3] = (uint32)f2bf(f1.z) | ((uint32)f2bf(f1.w) << 16);
                    af = pk.v;
                }
                #pragma unroll
                for (int n = 0; n < NT; n++)
                    acc[rs][n] = __builtin_amdgcn_mfma_f32_16x16x32_bf16(af, bf[n], acc[rs][n], 0, 0, 0);
            }
        }
        #pragma unroll
        for (int rs = 0; rs < 2; rs++) {
            #pragma unroll
            for (int r = 0; r < 4; r++) {
                const int row = rbase + rs * 16 + lgrp * 4 + r;
                if (row < M) {
                    if constexpr (OUT8) {
                        uchar8* H8 = (uchar8*)Houtv;
                        #pragma unroll
                        for (int n = 0; n < HT; n++) {
                            int pk = __builtin_amdgcn_cvt_pk_fp8_f32(acc[rs][n][r], 0.f, 0, false);
                            H8[(long)row * (HT * 16) + n * 16 + lrow] = (uchar8)pk;
                        }
                    } else {
                        ushort16* Hh = (ushort16*)Houtv;
                        #pragma unroll
                        for (int n = 0; n < HT; n++)
                            Hh[(long)row * (HT * 16) + n * 16 + lrow] = f2bf(acc[rs][n][r]);
                    }
                    if (lrow < 2 * NH)
                        asd[(long)row * (2 * NH) + lrow] = acc[rs][NT - 1][r];
                }
            }
        }
    }
}

// ================= CSR build via two-level multisplit (no global atomics) =============
__global__ __launch_bounds__(256) void buck_hist_k(
    const int* __restrict__ ei, int E, int Etot,
    int* __restrict__ cnt_bb, int NBUK_, int NBLK_)
{
    __shared__ int hist[1024];
    const int b = blockIdx.x, t = threadIdx.x;
    for (int i = t; i < NBUK_; i += 256) hist[i] = 0;
    __syncthreads();
    const int e0 = b * EPB;
    for (int i = t; i < EPB; i += 256) {
        int e = e0 + i;
        if (e < Etot) {
            int d = (e < E) ? ei[E + e] : (e - E);
            atomicAdd(&hist[d >> 7], 1);
        }
    }
    __syncthreads();
    for (int i = t; i < NBUK_; i += 256) cnt_bb[(size_t)i * NBLK_ + b] = hist[i];
}

__global__ __launch_bounds__(256) void buck_scan_row_k(
    int* __restrict__ cnt_bb, int* __restrict__ rowTot, int NBLK_)
{
    __shared__ int tmp[256];
    const int k = blockIdx.x, t = threadIdx.x;
    int* row = cnt_bb + (size_t)k * NBLK_;
    const int base = t * 4;
    int v[4]; int s = 0;
    #pragma unroll
    for (int j = 0; j < 4; j++) { v[j] = (base + j < NBLK_) ? row[base + j] : 0; s += v[j]; }
    tmp[t] = s; __syncthreads();
    for (int off = 1; off < 256; off <<= 1) {
        int x = (t >= off) ? tmp[t - off] : 0;
        __syncthreads();
        tmp[t] += x;
        __syncthreads();
    }
    int run = tmp[t] - s;
    if (t == 255) rowTot[k] = tmp[255];
    #pragma unroll
    for (int j = 0; j < 4; j++) { if (base + j < NBLK_) row[base + j] = run; run += v[j]; }
}

__global__ __launch_bounds__(256) void buck_base_k(
    const int* __restrict__ rowTot, int* __restrict__ bucketBase, int NBUK_)
{
    __shared__ int tmp[256];
    const int t = threadIdx.x;
    const int base = t * 4;
    int v[4]; int s = 0;
    #pragma unroll
    for (int j = 0; j < 4; j++) {
        v[j] = (base + j < NBUK_) ? ((rowTot[base + j] + 3 * DPB + 7) & ~7) : 0;
        s += v[j];
    }
    tmp[t] = s; __syncthreads();
    for (int off = 1; off < 256; off <<= 1) {
        int x = (t >= off) ? tmp[t - off] : 0;
        __syncthreads();
        tmp[t] += x;
        __syncthreads();
    }
    int run = tmp[t] - s;
    #pragma unroll
    for (int j = 0; j < 4; j++) { if (base + j < NBUK_) bucketBase[base + j] = run; run += v[j]; }
}

__global__ __launch_bounds__(256) void buck_scatter_k(
    const int* __restrict__ ei, int E, int Etot,
    const int* __restrict__ cnt_bb, const int* __restrict__ bucketBase,
    uint32* __restrict__ be, int NBUK_, int NBLK_)
{
    __shared__ int cur[1024];
    const int b = blockIdx.x, t = threadIdx.x;
    for (int i = t; i < NBUK_; i += 256)
        cur[i] = bucketBase[i] + cnt_bb[(size_t)i * NBLK_ + b];
    __syncthreads();
    const int e0 = b * EPB;
    for (int i = t; i < EPB; i += 256) {
        int e = e0 + i;
        if (e < Etot) {
            int srcv, d;
            if (e < E) { srcv = ei[e]; d = ei[E + e]; } else { srcv = d = e - E; }
            int slot = atomicAdd(&cur[d >> 7], 1);
            be[slot] = (uint32)srcv | ((uint32)(d & (DPB - 1)) << 20);
        }
    }
}

// Per bucket: hist/scan (x4-padded), write indptr/count, rank+scatter into LDS image,
// flush CSR coalesced AND compute layer-1 p planes (fused former edge_p_k).
// CSR stores PRE-SHIFTED byte offsets (src<<7); pad slots: csr=0, p=0.
// No-max softmax is safe: |logit| < ~5 for this model, exp cannot overflow.
__global__ __launch_bounds__(256) void buck_finalize_k(
    const uint32* __restrict__ be, const int* __restrict__ rowTot,
    const int* __restrict__ bucketBase, const float* __restrict__ asd1,
    int* __restrict__ csr, int* __restrict__ indptr, int* __restrict__ count,
    ushort16* __restrict__ p1h, int N_, int EP)
{
    __shared__ int lhist[DPB];
    __shared__ int lptr[DPB];
    __shared__ int lcur[DPB];
    __shared__ int stmp[DPB];
    __shared__ int img[6144];
    __shared__ short slot2d[6144];
    __shared__ float4 adl[DPB];
    __shared__ int paddedTotS;
    const int k = blockIdx.x, t = threadIdx.x;
    const int baseG = bucketBase[k];
    const int Mk = rowTot[k];
    if (t < DPB) lhist[t] = 0;
    __syncthreads();
    for (int i = t; i < Mk; i += 256) atomicAdd(&lhist[be[baseG + i] >> 20], 1);
    __syncthreads();
    int myp = (t < DPB) ? ((lhist[t] + 3) & ~3) : 0;
    if (t < DPB) stmp[t] = myp;
    __syncthreads();
    for (int off = 1; off < DPB; off <<= 1) {
        int x = (t < DPB && t >= off) ? stmp[t - off] : 0;
        __syncthreads();
        if (t < DPB) stmp[t] += x;
        __syncthreads();
    }
    if (t < DPB) { lptr[t] = stmp[t] - myp; lcur[t] = stmp[t] - myp; }
    if (t == DPB - 1) paddedTotS = stmp[t];
    __syncthreads();
    const int paddedTot = paddedTotS < 6144 ? paddedTotS : 6144;
    for (int i = t; i < paddedTot; i += 256) { img[i] = 0; slot2d[i] = -1; }
    if (t < DPB) {
        int d = k * DPB + t;
        if (d < N_) {
            count[d] = lhist[t];
            indptr[d] = baseG + lptr[t];
            adl[t] = *(const float4*)&asd1[(size_t)d * 8 + 4];
        }
    }
    __syncthreads();
    for (int i = t; i < Mk; i += 256) {
        uint32 pk = be[baseG + i];
        int dloc = (int)(pk >> 20);
        int slot = atomicAdd(&lcur[dloc], 1);
        if (slot < 6144) {
            img[slot] = (int)((pk & 0xFFFFFu) << 7);   // pre-shifted byte offset
            slot2d[slot] = (short)dloc;
        }
    }
    __syncthreads();
    const char* asdb = (const char*)asd1;
    for (int i = t; i < paddedTot; i += 256) {
        const int sb = img[i];
        csr[baseG + i] = sb;
        const int dloc = slot2d[i];
        ushort16 r0 = 0, r1 = 0, r2 = 0, r3 = 0;
        if (dloc >= 0) {
            float4 as = *(const float4*)(asdb + (((uint32)sb) >> 2));   // src*32
            float4 ad = adl[dloc];
            float e0 = as.x + ad.x, e1 = as.y + ad.y, e2 = as.z + ad.z, e3 = as.w + ad.w;
            e0 = e0 >= 0.f ? e0 : NEG_SLOPE * e0;
            e1 = e1 >= 0.f ? e1 : NEG_SLOPE * e1;
            e2 = e2 >= 0.f ? e2 : NEG_SLOPE * e2;
            e3 = e3 >= 0.f ? e3 : NEG_SLOPE * e3;
            r0 = f2bf(__expf(e0)); r1 = f2bf(__expf(e1));
            r2 = f2bf(__expf(e2)); r3 = f2bf(__expf(e3));
        }
        const int pos = baseG + i;
        p1h[pos] = r0;
        p1h[EP + pos] = r1;
        p1h[2 * EP + pos] = r2;
        p1h[3 * EP + pos] = r3;
    }
}

// ================= layer-2 per-edge softmax weights ===================================
__global__ __launch_bounds__(256) void edge_p2_k(
    const int* __restrict__ csr, const int* __restrict__ indptr, const int* __restrict__ count,
    const float* __restrict__ asd2, ushort16* __restrict__ p2, int N)
{
    int wave = threadIdx.x >> 6, lane = threadIdx.x & 63;
    int dst = blockIdx.x * 4 + wave;
    if (dst >= N) return;
    const char* asdb = (const char*)asd2;
    const int start = indptr[dst], cnt = count[dst];
    const int cntp = (cnt + 3) & ~3;
    const float ad = *(const float*)(asdb + (((uint32)dst << 3) | 4u));
    for (int k = lane; k < cntp; k += 64) {
        ushort16 r = 0;
        if (k < cnt) {
            uint32 sb = (uint32)csr[start + k];
            float el = *(const float*)(asdb + (sb >> 4)) + ad;   // src*8
            el = el >= 0.f ? el : NEG_SLOPE * el;
            r = f2bf(__expf(el));
        }
        p2[start + k] = r;
    }
}

// ---------------- layer-1 aggregation: fp8 H, head-major p, 8-edge pipeline ----------
// One wave per dst; lane l -> channels 2l,2l+1, head = l>>4. relu(+b1) folded; bf16 out.
// csr holds src<<7; addr = sb | lane*2 (32-bit).
__global__ __launch_bounds__(256) void agg_flash_h4(
    const int* __restrict__ csr, const ushort16* __restrict__ p1h,
    const int* __restrict__ indptr, const int* __restrict__ count,
    const uchar8* __restrict__ H8, const float* __restrict__ b1,
    uint32* __restrict__ Out, int N, int EP)
{
    int wave = threadIdx.x >> 6, lane = threadIdx.x & 63;
    int dst = blockIdx.x * 4 + wave;
    if (dst >= N) return;
    const char* Hb = (const char*)H8;
    const int head = lane >> 4;
    const uint32 ch2 = (uint32)(lane * 2);
    const int start = indptr[dst], cnt = count[dst];
    const int cntp = (cnt + 3) & ~3;
    const ushort16* pp = p1h + (size_t)head * EP + start;
    float s = 0.f, a0 = 0.f, a1 = 0.f;
    int k = 0;
    for (; k + 8 <= cntp; k += 8) {   // two 4-edge groups, 8 gathers in flight
        const int4 svA = *(const int4*)&csr[start + k];
        const int4 svB = *(const int4*)&csr[start + k + 4];
        const uint2 pwA = *(const uint2*)&pp[k];
        const uint2 pwB = *(const uint2*)&pp[k + 4];
        const uint32 u0 = *(const ushort16*)(Hb + ((uint32)svA.x | ch2));
        const uint32 u1 = *(const ushort16*)(Hb + ((uint32)svA.y | ch2));
        const uint32 u2 = *(const ushort16*)(Hb + ((uint32)svA.z | ch2));
        const uint32 u3 = *(const ushort16*)(Hb + ((uint32)svA.w | ch2));
        const uint32 u4 = *(const ushort16*)(Hb + ((uint32)svB.x | ch2));
        const uint32 u5 = *(const ushort16*)(Hb + ((uint32)svB.y | ch2));
        const uint32 u6 = *(const ushort16*)(Hb + ((uint32)svB.z | ch2));
        const uint32 u7 = *(const ushort16*)(Hb + ((uint32)svB.w | ch2));
        const f32x2 h0 = __builtin_amdgcn_cvt_pk_f32_fp8((int)u0, false);
        const f32x2 h1 = __builtin_amdgcn_cvt_pk_f32_fp8((int)u1, false);
        const f32x2 h2 = __builtin_amdgcn_cvt_pk_f32_fp8((int)u2, false);
        const f32x2 h3 = __builtin_amdgcn_cvt_pk_f32_fp8((int)u3, false);
        const f32x2 h4 = __builtin_amdgcn_cvt_pk_f32_fp8((int)u4, false);
        const f32x2 h5 = __builtin_amdgcn_cvt_pk_f32_fp8((int)u5, false);
        const f32x2 h6 = __builtin_amdgcn_cvt_pk_f32_fp8((int)u6, false);
        const f32x2 h7 = __builtin_amdgcn_cvt_pk_f32_fp8((int)u7, false);
        const float p0 = bf2f_lo(pwA.x), p1v = bf2f_hi(pwA.x);
        const float p2v = bf2f_lo(pwA.y), p3v = bf2f_hi(pwA.y);
        const float p4v = bf2f_lo(pwB.x), p5v = bf2f_hi(pwB.x);
        const float p6v = bf2f_lo(pwB.y), p7v = bf2f_hi(pwB.y);
        s += ((p0 + p1v) + (p2v + p3v)) + ((p4v + p5v) + (p6v + p7v));
        a0 += p0 * h0[0];  a1 += p0 * h0[1];
        a0 += p1v * h1[0]; a1 += p1v * h1[1];
        a0 += p2v * h2[0]; a1 += p2v * h2[1];
        a0 += p3v * h3[0]; a1 += p3v * h3[1];
        a0 += p4v * h4[0]; a1 += p4v * h4[1];
        a0 += p5v * h5[0]; a1 += p5v * h5[1];
        a0 += p6v * h6[0]; a1 += p6v * h6[1];
        a0 += p7v * h7[0]; a1 += p7v * h7[1];
    }
    if (k < cntp) {                   // remaining 4-edge group
        const int4 sv = *(const int4*)&csr[start + k];
        const uint2 pw = *(const uint2*)&pp[k];
        const uint32 u0 = *(const ushort16*)(Hb + ((uint32)sv.x | ch2));
        const uint32 u1 = *(const ushort16*)(Hb + ((uint32)sv.y | ch2));
        const uint32 u2 = *(const ushort16*)(Hb + ((uint32)sv.z | ch2));
        const uint32 u3 = *(const ushort16*)(Hb + ((uint32)sv.w | ch2));
        const f32x2 h0 = __builtin_amdgcn_cvt_pk_f32_fp8((int)u0, false);
        const f32x2 h1 = __builtin_amdgcn_cvt_pk_f32_fp8((int)u1, false);
        const f32x2 h2 = __builtin_amdgcn_cvt_pk_f32_fp8((int)u2, false);
        const f32x2 h3 = __builtin_amdgcn_cvt_pk_f32_fp8((int)u3, false);
        const float p0 = bf2f_lo(pw.x), p1v = bf2f_hi(pw.x);
        const float p2v = bf2f_lo(pw.y), p3v = bf2f_hi(pw.y);
        s += (p0 + p1v) + (p2v + p3v);
        a0 += p0 * h0[0];  a1 += p0 * h0[1];
        a0 += p1v * h1[0]; a1 += p1v * h1[1];
        a0 += p2v * h2[0]; a1 += p2v * h2[1];
        a0 += p3v * h3[0]; a1 += p3v * h3[1];
    }
    const float inv = 1.f / s;
    const float2 bb = *(const float2*)&b1[ch2];
    float o0 = fmaxf(a0 * inv + bb.x, 0.f);
    float o1 = fmaxf(a1 * inv + bb.y, 0.f);
    Out[(long)dst * 64 + lane] = (uint32)f2bf(o0) | ((uint32)f2bf(o1) << 16);
}

// ---------------- layer-2 aggregation: fp8 H2, 4 groups x 4-edge unroll ---------------
// csr holds src<<7; addr = (sb>>2) | c2*2.
__global__ __launch_bounds__(256) void agg_flash_h1(
    const int* __restrict__ csr, const ushort16* __restrict__ p2,
    const int* __restrict__ indptr, const int* __restrict__ count,
    const uchar8* __restrict__ H8, float* __restrict__ Out, int N)
{
    int wave = threadIdx.x >> 6, lane = threadIdx.x & 63;
    int dst = blockIdx.x * 4 + wave;
    if (dst >= N) return;
    const char* Hb = (const char*)H8;
    const int c2 = lane & 15, grp = lane >> 4;
    const uint32 cb = (uint32)(c2 * 2);
    const int start = indptr[dst];
    const int cntp = (count[dst] + 3) & ~3;
    float s = 0.f, a0 = 0.f, a1 = 0.f;
    for (int k = grp * 4; k < cntp; k += 16) {
        const int4  sv = *(const int4*)&csr[start + k];
        const uint2 pv = *(const uint2*)&p2[start + k];
        const uint32 u0 = *(const ushort16*)(Hb + (((uint32)sv.x >> 2) | cb));
        const uint32 u1 = *(const ushort16*)(Hb + (((uint32)sv.y >> 2) | cb));
        const uint32 u2 = *(const ushort16*)(Hb + (((uint32)sv.z >> 2) | cb));
        const uint32 u3 = *(const ushort16*)(Hb + (((uint32)sv.w >> 2) | cb));
        const f32x2 h0 = __builtin_amdgcn_cvt_pk_f32_fp8((int)u0, false);
        const f32x2 h1 = __builtin_amdgcn_cvt_pk_f32_fp8((int)u1, false);
        const f32x2 h2 = __builtin_amdgcn_cvt_pk_f32_fp8((int)u2, false);
        const f32x2 h3 = __builtin_amdgcn_cvt_pk_f32_fp8((int)u3, false);
        float q0 = bf2f_lo(pv.x), q1 = bf2f_hi(pv.x);
        float q2 = bf2f_lo(pv.y), q3 = bf2f_hi(pv.y);
        s += (q0 + q1) + (q2 + q3);
        a0 += q0 * h0[0]; a1 += q0 * h0[1];
        a0 += q1 * h1[0]; a1 += q1 * h1[1];
        a0 += q2 * h2[0]; a1 += q2 * h2[1];
        a0 += q3 * h3[0]; a1 += q3 * h3[1];
    }
    s  += __shfl_xor(s, 16, 64);  s  += __shfl_xor(s, 32, 64);
    a0 += __shfl_xor(a0, 16, 64); a0 += __shfl_xor(a0, 32, 64);
    a1 += __shfl_xor(a1, 16, 64); a1 += __shfl_xor(a1, 32, 64);
    if (grp == 0) {
        const float inv = 1.f / s;
        float2 o; o.x = a0 * inv; o.y = a1 * inv;
        *(float2*)&Out[(long)dst * 32 + c2 * 2] = o;
    }
}

// ---------------- fused mean-pool + FC: one block per graph, zero atomics -------------
__global__ __launch_bounds__(256) void pool_fc_kernel(
    const float* __restrict__ Agg2, const float* __restrict__ b2,
    const int* __restrict__ batch,
    const float* __restrict__ Wfc, const float* __restrict__ bfc,
    float* __restrict__ out, int N)
{
    __shared__ float part[8][32];
    const int g = blockIdx.x;
    const int t = threadIdx.x;
    const int c = t & 31, grp = t >> 5;

    int lo = 0, hi = N;
    while (lo < hi) { int mid = (lo + hi) >> 1; if (batch[mid] < g) lo = mid + 1; else hi = mid; }
    const int start = lo;
    hi = N;
    while (lo < hi) { int mid = (lo + hi) >> 1; if (batch[mid] <= g) lo = mid + 1; else hi = mid; }
    const int end = lo;

    const float bc = b2[c];
    float acc = 0.f;
    for (int i = start + grp; i < end; i += 8)
        acc += fmaxf(Agg2[(long)i * 32 + c] + bc, 0.f);
    part[grp][c] = acc;
    __syncthreads();
    if (t < 32) {
        float s = 0.f;
        #pragma unroll
        for (int r = 0; r < 8; r++) s += part[r][c];
        const float cnt = fmaxf((float)(end - start), 1.f);
        float v = (s / cnt) * Wfc[c];
        #pragma unroll
        for (int m = 16; m >= 1; m >>= 1) v += __shfl_xor(v, m, 64);
        if (c == 0) out[g] = v + bfc[0];
    }
}

extern "C" void kernel_launch(void* const* d_in, const int* in_sizes, int n_in,
                              void* d_out, int out_size, void* d_ws, size_t ws_size,
                              hipStream_t stream)
{
    const float* x     = (const float*)d_in[0];
    const int*   ei    = (const int*)d_in[1];
    const int*   batch = (const int*)d_in[2];
    const float* W1    = (const float*)d_in[3];
    const float* atts1 = (const float*)d_in[4];
    const float* attd1 = (const float*)d_in[5];
    const float* b1    = (const float*)d_in[6];
    const float* W2    = (const float*)d_in[7];
    const float* atts2 = (const float*)d_in[8];
    const float* attd2 = (const float*)d_in[9];
    const float* b2    = (const float*)d_in[10];
    const float* Wfc   = (const float*)d_in[11];
    const float* bfc   = (const float*)d_in[12];
    float* out = (float*)d_out;

    const int N = in_sizes[0] / 128;
    const int E = in_sizes[1] / 2;
    const int Etot = E + N;
    const int G = out_size;
    const int NBUK = (N + DPB - 1) / DPB;
    const int NBLK = (Etot + EPB - 1) / EPB;
    const int CSRCAP = (Etot + NBUK * (3 * DPB + 8) + 7) & ~7;
    const int ntiles = (N + 127) >> 7;

    float* w = (float*)d_ws;
    uchar8* h1   = (uchar8*)w; w += (size_t)N * 32;   // N*128 fp8
    uchar8* h2   = (uchar8*)w; w += (size_t)N * 8;    // N*32 fp8
    uint32* agg1 = (uint32*)w; w += (size_t)N * 64;   // N*128 bf16 (= relu'd layer-2 X)
    float* agg2 = w; w += (size_t)N * 32;
    float* asd1 = w; w += (size_t)N * 8;              // {as[4], ad[4]}
    float* asd2 = w; w += (size_t)N * 2;              // {as, ad}
    ushort16* Bt1 = (ushort16*)w; w += (144 * 128) / 2;
    ushort16* Bt2 = (ushort16*)w; w += (48 * 128) / 2;
    int* count  = (int*)w; w += N;
    int* indptr = (int*)w; w += N;
    int* cnt_bb = (int*)w; w += (size_t)NBUK * NBLK;
    int* rowTot = (int*)w; w += NBUK;
    int* bucketBase = (int*)w; w += NBUK;
    uint32* be  = (uint32*)w; w += CSRCAP;
    int* csr    = (int*)w; w += CSRCAP;
    ushort16* p1h = (ushort16*)w; w += (size_t)CSRCAP * 2;  // 4 head planes bf16
    ushort16* p2  = (ushort16*)w; w += CSRCAP / 2;

    // prep B matrices (both layers, one kernel)
    prep_B<<<(192 * 128 + 255) / 256, 256, 0, stream>>>(W1, atts1, attd1, W2, atts2, attd2, Bt1, Bt2);

    // layer-1 GEMM (MFMA bf16): fp8 h1 + f32 asd1; exact tile grid
    gemm_mfma<9, 4, false, true><<<ntiles, 256, 0, stream>>>(x, Bt1, h1, asd1, N);

    // CSR build: two-level multisplit, no global atomics; csr holds src<<7;
    // finalize also emits layer-1 p planes (fused)
    buck_hist_k<<<NBLK, 256, 0, stream>>>(ei, E, Etot, cnt_bb, NBUK, NBLK);
    buck_scan_row_k<<<NBUK, 256, 0, stream>>>(cnt_bb, rowTot, NBLK);
    buck_base_k<<<1, 256, 0, stream>>>(rowTot, bucketBase, NBUK);
    buck_scatter_k<<<NBLK, 256, 0, stream>>>(ei, E, Etot, cnt_bb, bucketBase, be, NBUK, NBLK);
    buck_finalize_k<<<NBUK, 256, 0, stream>>>(be, rowTot, bucketBase, asd1,
                                              csr, indptr, count, p1h, N, CSRCAP);

    // layer-1 aggregation
    agg_flash_h4<<<(N + 3) / 4, 256, 0, stream>>>(csr, p1h, indptr, count, h1, b1, agg1, N, CSRCAP);

    // layer-2 GEMM (MFMA bf16, bf16 A direct): fp8 h2 + f32 asd2
    gemm_mfma<3, 1, true, true><<<ntiles, 256, 0, stream>>>(agg1, Bt2, h2, asd2, N);
    edge_p2_k<<<(N + 3) / 4, 256, 0, stream>>>(csr, indptr, count, asd2, p2, N);
    agg_flash_h1<<<(N + 3) / 4, 256, 0, stream>>>(csr, p2, indptr, count, h2, agg2, N);

    // fused mean-pool + FC
    pool_fc_kernel<<<G, 256, 0, stream>>>(agg2, b2, batch, Wfc, bfc, out, N);
}